// Round 11
// baseline (155.764 us; speedup 1.0000x reference)
//
#include <hip/hip_runtime.h>
#include <hip/hip_bf16.h>

#define SEQ 2048
#define QSTR 4096
// (1/sqrt(128)) * log2(e)
#define CSCALE 0.1275174364688796f

typedef __attribute__((ext_vector_type(8)))  short short8;
typedef __attribute__((ext_vector_type(4)))  float f32x4;
typedef __attribute__((ext_vector_type(16))) float f32x16;

union PF8 { unsigned u[4]; short8 s; };

__device__ __forceinline__ unsigned short f2bf(float f) {
    union { __hip_bfloat16 b; unsigned short u; } cv;
    cv.b = __float2bfloat16(f);
    return cv.u;
}
__device__ __forceinline__ float bf2f(unsigned short u) {
    unsigned v = ((unsigned)u) << 16;
    return __builtin_bit_cast(float, v);
}

// ---- prepass: K -> bf16 [hk][kv][d] ----
__global__ void prep_k(const float* __restrict__ Kg, unsigned short* __restrict__ Kb) {
    int gi = blockIdx.x * 256 + threadIdx.x;
    int kv = gi >> 8;
    int rem = gi & 255;
    int hk = rem >> 5;
    int d4 = rem & 31;
    f32x4 k4 = *(const f32x4*)(Kg + ((size_t)kv * 8 + hk) * 128 + 4 * d4);
    ushort4 u = make_ushort4(f2bf(k4[0]), f2bf(k4[1]), f2bf(k4[2]), f2bf(k4[3]));
    *(ushort4*)(Kb + ((size_t)hk * SEQ + kv) * 128 + 4 * d4) = u;
}

// ---- prepass: V -> bf16 transposed [hk][d][kv] ----
__global__ void prep_v(const float* __restrict__ Vg, unsigned short* __restrict__ Vtb) {
    const int hk  = blockIdx.x >> 5;
    const int kvb = blockIdx.x & 31;
    __shared__ unsigned short T[128][72];
    const int t = threadIdx.x;
    #pragma unroll
    for (int i = 0; i < 8; ++i) {
        int idx = t + 256 * i;
        int r = idx >> 5, d4 = idx & 31;
        f32x4 v = *(const f32x4*)(Vg + ((size_t)(kvb * 64 + r) * 8 + hk) * 128 + 4 * d4);
        T[4 * d4 + 0][r] = f2bf(v[0]);
        T[4 * d4 + 1][r] = f2bf(v[1]);
        T[4 * d4 + 2][r] = f2bf(v[2]);
        T[4 * d4 + 3][r] = f2bf(v[3]);
    }
    __syncthreads();
    #pragma unroll
    for (int i = 0; i < 8; ++i) {
        int idx = t + 256 * i;
        int d = idx >> 4, c4 = idx & 15;
        ushort4 u = *(ushort4*)&T[d][4 * c4];
        *(ushort4*)(Vtb + ((size_t)hk * 128 + d) * SEQ + kvb * 64 + 4 * c4) = u;
    }
}

__launch_bounds__(128, 2)
__global__ void attn_fwd(const float* __restrict__ Qg,
                         const unsigned short* __restrict__ Kb,
                         const unsigned short* __restrict__ Vtb,
                         float* __restrict__ Og) {
    const int bid = blockIdx.x;        // 1024 = 32 pairs x 32 heads, ALL uniform
    const int p   = bid >> 5;          // 0..31
    const int h   = bid & 31;
    const int hk  = h >> 2;
    const int tb  = 63 - p;            // big 32-row q-tile (phase 0)
    const int ta  = p;                 // small (phase 1); (tb+1)+(ta+1) == 65

    const int tid  = threadIdx.x;
    const int wk   = tid >> 6;         // wave 0/1: alternating kv tiles
    const int lane = tid & 63;
    const int q5   = lane & 31;
    const int t5   = lane >> 5;

    __shared__ float mstat[2][2][32];
    __shared__ unsigned short Otb[32][136];

    const unsigned short* Kh = Kb  + (size_t)hk * SEQ * 128;
    const unsigned short* Vh = Vtb + (size_t)hk * 128 * SEQ;

    short8 kA[8], kB[8], vR[8], qf[8];
    f32x16 oacc[4];
    float m, l;

    auto LOADK = [&](short8 (&ks8)[8], int kv0) __attribute__((always_inline)) {
        const unsigned short* kp = Kh + (size_t)(kv0 + q5) * 128 + 8 * t5;
        #pragma unroll
        for (int st = 0; st < 8; ++st)
            ks8[st] = *(const short8*)(kp + 16 * st);
    };
    auto LOADV = [&](int kv0) __attribute__((always_inline)) {
        #pragma unroll
        for (int dt = 0; dt < 4; ++dt)
            #pragma unroll
            for (int ks = 0; ks < 2; ++ks)
                vR[2 * dt + ks] = *(const short8*)
                    (Vh + (size_t)(32 * dt + q5) * SEQ + kv0 + 16 * ks + 8 * t5);
    };

    // one kv tile: QK -> softmax (in-register, R10-verbatim) -> PV; prefetches inline
    auto STEP = [&](short8 (&kset)[8], int j, int q0, int qt, int nw)
        __attribute__((always_inline)) {
        const int kv0 = 32 * (2 * j + wk);

        // ---- S^T = K Q^T : D[row=kv][col=q5] ----
        f32x16 sac;
        #pragma unroll
        for (int r = 0; r < 16; ++r) sac[r] = 0.f;
        __builtin_amdgcn_s_setprio(1);
        #pragma unroll
        for (int st = 0; st < 8; ++st)
            sac = __builtin_amdgcn_mfma_f32_32x32x16_bf16(kset[st], qf[st], sac, 0, 0, 0);
        __builtin_amdgcn_s_setprio(0);

        // prefetch K two tiles ahead into the set just consumed
        if (j + 2 < nw) LOADK(kset, 32 * (2 * j + 4 + wk));

        // ---- mask (diagonal tile only) ----
        if (kv0 + 31 > q0) {
            const int qrow = q0 + q5;
            #pragma unroll
            for (int r = 0; r < 16; ++r) {
                int kv = kv0 + (r & 3) + 8 * (r >> 2) + 4 * t5;
                if (kv > qrow) sac[r] = -1e30f;
            }
        }

        // ---- row max: depth-4 tree + one cross-lane ----
        float m8[8], m4[4], m2[2];
        #pragma unroll
        for (int i = 0; i < 8; ++i) m8[i] = fmaxf(sac[i], sac[i + 8]);
        #pragma unroll
        for (int i = 0; i < 4; ++i) m4[i] = fmaxf(m8[i], m8[i + 4]);
        m2[0] = fmaxf(m4[0], m4[2]); m2[1] = fmaxf(m4[1], m4[3]);
        float mx = fmaxf(m2[0], m2[1]);
        mx = fmaxf(mx, __shfl_xor(mx, 32));

        // ---- defer-max (T13) ----
        const bool skip = __all(mx <= m + 11.0f);
        float fac = 1.0f;
        if (!skip) {
            float mn = fmaxf(m, mx);
            fac = exp2f(m - mn);
            m = mn;
        }

        // ---- P = 2^(S-m); depth-4 tree sum ----
        #pragma unroll
        for (int r = 0; r < 16; ++r) sac[r] = exp2f(sac[r] - m);
        float s8[8], s4[4], s2[2];
        #pragma unroll
        for (int i = 0; i < 8; ++i) s8[i] = sac[i] + sac[i + 8];
        #pragma unroll
        for (int i = 0; i < 4; ++i) s4[i] = s8[i] + s8[i + 4];
        s2[0] = s4[0] + s4[2]; s2[1] = s4[1] + s4[3];
        float ps = s2[0] + s2[1];
        ps += __shfl_xor(ps, 32);
        if (!skip) {
            l = l * fac + ps;
            #pragma unroll
            for (int dt = 0; dt < 4; ++dt)
                #pragma unroll
                for (int r = 0; r < 16; ++r) oacc[dt][r] *= fac;
        } else {
            l += ps;
        }

        // ---- pack P pairs to bf16x2 ----
        unsigned pkw[8];
        #pragma unroll
        for (int rp = 0; rp < 8; ++rp)
            pkw[rp] = (unsigned)f2bf(sac[2 * rp]) |
                      ((unsigned)f2bf(sac[2 * rp + 1]) << 16);

        // ---- redistribute to PV B-fragments (cross-half only) ----
        unsigned xp[8];
        #pragma unroll
        for (int i = 0; i < 8; ++i)
            xp[i] = (unsigned)__shfl_xor((int)pkw[i], 32);

        PF8 pf[2];
        #pragma unroll
        for (int ks = 0; ks < 2; ++ks) {
            #pragma unroll
            for (int j4 = 0; j4 < 4; ++j4) {
                const int ib = (j4 & 1) + 4 * ks;
                const unsigned own_lo = pkw[ib];
                const unsigned own_hi = pkw[ib + 2];
                const unsigned par_lo = xp[ib];
                const unsigned par_hi = xp[ib + 2];
                pf[ks].u[j4] = (j4 < 2) ? (t5 ? par_hi : own_lo)
                                        : (t5 ? own_hi : par_lo);
            }
        }

        // ---- O^T += V^T P ----
        __builtin_amdgcn_s_setprio(1);
        #pragma unroll
        for (int dt = 0; dt < 4; ++dt)
            #pragma unroll
            for (int ks = 0; ks < 2; ++ks)
                oacc[dt] = __builtin_amdgcn_mfma_f32_32x32x16_bf16(
                    vR[2 * dt + ks], pf[ks].s, oacc[dt], 0, 0, 0);
        __builtin_amdgcn_s_setprio(0);

        // prefetch V one tile ahead
        if (j + 1 < nw) LOADV(32 * (2 * j + 2 + wk));
    };

    #pragma unroll 1
    for (int ph = 0; ph < 2; ++ph) {
        const int qt = ph ? ta : tb;
        const int q0 = 32 * qt;
        const int nw = (qt + 2 - wk) >> 1;   // this wave's tile count

        // ---- Q fragments (scale folded) ----
        {
            const float* qp = Qg + (size_t)(q0 + q5) * QSTR + h * 128 + 8 * t5;
            #pragma unroll
            for (int st = 0; st < 8; ++st) {
                f32x4 a = *(const f32x4*)(qp + 16 * st);
                f32x4 c = *(const f32x4*)(qp + 16 * st + 4);
                short8 f;
                f[0] = (short)f2bf(a[0] * CSCALE); f[1] = (short)f2bf(a[1] * CSCALE);
                f[2] = (short)f2bf(a[2] * CSCALE); f[3] = (short)f2bf(a[3] * CSCALE);
                f[4] = (short)f2bf(c[0] * CSCALE); f[5] = (short)f2bf(c[1] * CSCALE);
                f[6] = (short)f2bf(c[2] * CSCALE); f[7] = (short)f2bf(c[3] * CSCALE);
                qf[st] = f;
            }
        }
        #pragma unroll
        for (int dt = 0; dt < 4; ++dt)
            #pragma unroll
            for (int r = 0; r < 16; ++r) oacc[dt][r] = 0.f;
        m = -1e30f; l = 0.f;

        if (nw > 0) {
            LOADK(kA, 32 * wk);
            LOADV(32 * wk);
            if (nw > 1) LOADK(kB, 32 * (2 + wk));
            #pragma unroll 1
            for (int j = 0; j < nw; j += 2) {
                STEP(kA, j, q0, qt, nw);
                if (j + 1 < nw) STEP(kB, j + 1, q0, qt, nw);
            }
        }

        // ---- EPI: 2-wave combine (flash-decoding algebra) + store ----
        if (t5 == 0) mstat[0][wk][q5] = m;
        __syncthreads();
        const float mo = mstat[0][wk ^ 1][q5];
        const float M  = fmaxf(m, mo);
        const float sc = exp2f(m - M);
        #pragma unroll
        for (int dt = 0; dt < 4; ++dt)
            #pragma unroll
            for (int r = 0; r < 16; ++r) oacc[dt][r] *= sc;
        const float lp = l * sc;
        if (t5 == 0) mstat[1][wk][q5] = lp;
        __syncthreads();
        const float rl = 1.0f / (lp + mstat[1][wk ^ 1][q5]);

        if (wk == 1) {                    // publish partial (bf16)
            #pragma unroll
            for (int dt = 0; dt < 4; ++dt)
                #pragma unroll
                for (int ii = 0; ii < 4; ++ii) {
                    ushort4 u = make_ushort4(
                        f2bf(oacc[dt][4 * ii + 0]), f2bf(oacc[dt][4 * ii + 1]),
                        f2bf(oacc[dt][4 * ii + 2]), f2bf(oacc[dt][4 * ii + 3]));
                    *(ushort4*)&Otb[q5][32 * dt + 8 * ii + 4 * t5] = u;
                }
        }
        __syncthreads();
        if (wk == 0) {                    // combine + normalize
            #pragma unroll
            for (int dt = 0; dt < 4; ++dt)
                #pragma unroll
                for (int ii = 0; ii < 4; ++ii) {
                    ushort4 o1 = *(ushort4*)&Otb[q5][32 * dt + 8 * ii + 4 * t5];
                    ushort4 u = make_ushort4(
                        f2bf((oacc[dt][4 * ii + 0] + bf2f(o1.x)) * rl),
                        f2bf((oacc[dt][4 * ii + 1] + bf2f(o1.y)) * rl),
                        f2bf((oacc[dt][4 * ii + 2] + bf2f(o1.z)) * rl),
                        f2bf((oacc[dt][4 * ii + 3] + bf2f(o1.w)) * rl));
                    *(ushort4*)&Otb[q5][32 * dt + 8 * ii + 4 * t5] = u;
                }
        }
        __syncthreads();
        {   // both waves: coalesced fp32 store of the 32x128 tile
            #pragma unroll
            for (int i = 0; i < 8; ++i) {
                int ck = tid + 128 * i;          // 0..1023 f32x4-chunks
                int r  = ck >> 5;
                int c4 = (ck & 31) * 4;
                ushort4 u = *(ushort4*)&Otb[r][c4];
                f32x4 v;
                v[0] = bf2f(u.x); v[1] = bf2f(u.y);
                v[2] = bf2f(u.z); v[3] = bf2f(u.w);
                *(f32x4*)(Og + (size_t)(q0 + r) * QSTR + h * 128 + c4) = v;
            }
        }
        __syncthreads();                  // Otb/mstat safe for next phase
    }
}

extern "C" void kernel_launch(void* const* d_in, const int* in_sizes, int n_in,
                              void* d_out, int out_size, void* d_ws, size_t ws_size,
                              hipStream_t stream) {
    const float* q = (const float*)d_in[0];
    const float* k = (const float*)d_in[1];
    const float* v = (const float*)d_in[2];
    float* out = (float*)d_out;
    unsigned short* Kb  = (unsigned short*)d_ws;                 // 4 MB
    unsigned short* Vtb = Kb + (size_t)8 * SEQ * 128;            // 4 MB
    prep_k<<<dim3(2048), 256, 0, stream>>>(k, Kb);
    prep_v<<<dim3(256), 256, 0, stream>>>(v, Vtb);
    attn_fwd<<<dim3(1024), 128, 0, stream>>>(q, Kb, Vtb, out);
}